// Round 9
// baseline (407.489 us; speedup 1.0000x reference)
//
#include <hip/hip_runtime.h>

// ---------------- problem constants ----------------
constexpr int cB = 8, cN = 16384, cS = 1024, cK = 32, cD = 64;
constexpr int cO2 = 128;
constexpr int PTOT = cB * cS * cK;              // 262144 positions
constexpr int NBLK2 = PTOT / 128;               // 2048 conv blocks (128 positions each)

// output offsets (floats)
constexpr int OUT1_OFF = cB * 3 * cS;                    // 24576
constexpr int OUT2_OFF = OUT1_OFF + cB * cO2 * cS;       // 1073152
constexpr int OUT3_OFF = OUT2_OFF + cB * cS * cK * 3;    // 1859584

// workspace offsets (bytes) — y0 eliminated this round
constexpr size_t WS_PTS  = 0;                                         // [B][N][64] f32
constexpr size_t WS_XYZP = WS_PTS  + (size_t)cB * cN * cD * 4;        // [B][N] float4
constexpr size_t WS_IDX  = WS_XYZP + (size_t)cB * cN * 16;            // [P] int
constexpr size_t WS_NORM = WS_IDX  + (size_t)PTOT * 4;                // [P][3] f32
constexpr size_t WS_Y1   = WS_NORM + (size_t)PTOT * 3 * 4;           // [P][64] f32
constexpr size_t WS_MX   = WS_Y1   + (size_t)PTOT * 64 * 4;          // [B*S][128] f32
constexpr size_t WS_MN   = WS_MX   + (size_t)cB * cS * cO2 * 4;
constexpr size_t WS_P0   = WS_MN   + (size_t)cB * cS * cO2 * 4;      // [2048][64] float2
constexpr size_t WS_P1   = WS_P0   + (size_t)NBLK2 * 64 * 8;
constexpr size_t WS_P2   = WS_P1   + (size_t)NBLK2 * 64 * 8;         // [2048][128] float2
constexpr size_t WS_BN   = WS_P2   + (size_t)NBLK2 * 128 * 8;        // 3*128 float2
constexpr size_t WS_END  = WS_BN   + 3 * 128 * 2 * 4;

// ---------------- helpers ----------------
__device__ __forceinline__ unsigned keyOf(float d) {
    unsigned u = __float_as_uint(d);
    return u ^ ((unsigned)((int)u >> 31) | 0x80000000u);
}
// numpy-order, no-FMA distance: (ssq_q + ssq_p) - 2*((qx*px + qy*py) + qz*pz)
__device__ __forceinline__ float distNp(float qx, float qy, float qz, float sq, float4 p) {
    float m0 = __fmul_rn(qx, p.x);
    float m1 = __fmul_rn(qy, p.y);
    float m2 = __fmul_rn(qz, p.z);
    float dt = __fadd_rn(__fadd_rn(m0, m1), m2);
    return __fsub_rn(__fadd_rn(sq, p.w), __fmul_rn(2.0f, dt));
}

// ---------------- prep: transpose points + pack xyz (merged launch) ----------------
__global__ __launch_bounds__(256) void k_prep(const float* __restrict__ pts,
                                              const float* __restrict__ xyz,
                                              float* __restrict__ ptsT,
                                              float4* __restrict__ xyzp) {
    __shared__ float tile[64][65];
    int blk = blockIdx.x;
    int tid = threadIdx.x;
    if (blk < 2048) {
        int b = blk >> 8;
        int n0 = (blk & 255) * 64;
        for (int it = 0; it < 16; ++it) {
            int l = it * 256 + tid;
            int c = l >> 6, nn = l & 63;
            tile[nn][c] = pts[((size_t)b * 64 + c) * cN + n0 + nn];
        }
        __syncthreads();
        for (int it = 0; it < 16; ++it) {
            int l = it * 256 + tid;
            int nn = l >> 6, c = l & 63;
            ptsT[((size_t)(b * cN + n0 + nn)) * 64 + c] = tile[nn][c];
        }
    } else {
        int i = (blk - 2048) * 256 + tid;   // < B*N
        int b = i >> 14, n = i & (cN - 1);
        float x = xyz[(b * 3 + 0) * cN + n];
        float y = xyz[(b * 3 + 1) * cN + n];
        float z = xyz[(b * 3 + 2) * cN + n];
        float sq = __fadd_rn(__fadd_rn(__fmul_rn(x, x), __fmul_rn(y, y)), __fmul_rn(z, z));
        xyzp[i] = make_float4(x, y, z, sq);
    }
}

// ---------------- kNN (r3-proven): tight-R sampling + dense hist + dense collect ----------------
#define QB 8
#define CAP 256

__device__ __forceinline__ void selectBin2(const unsigned* __restrict__ h, int lane,
                                           int target, int* Tout, int* cbOut) {
    int base = lane * 8;
    unsigned hh[8];
    unsigned c8 = 0;
#pragma unroll
    for (int i = 0; i < 8; i++) { hh[i] = h[base + i]; c8 += hh[i]; }
    unsigned incl = c8;
#pragma unroll
    for (int off = 1; off < 32; off <<= 1) {
        unsigned t = __shfl_up(incl, (unsigned)off, 32);
        if (lane >= off) incl += t;
    }
    int excl = (int)(incl - c8);
    if (excl < target && target <= (int)incl) {
        int c = excl;
#pragma unroll
        for (int i = 0; i < 8; i++) {
            int nc = c + (int)hh[i];
            if (c < target && target <= nc) { *Tout = base + i; *cbOut = c; }
            c = nc;
        }
    }
}

__global__ __launch_bounds__(256, 4) void k_knn(const float* __restrict__ xyz,
                                                const int* __restrict__ sidx_g,
                                                const float4* __restrict__ xyzp,
                                                int* __restrict__ idxw,
                                                float* __restrict__ normw,
                                                float* __restrict__ outbuf) {
    __shared__ unsigned hist[QB][258];
    __shared__ unsigned long long cand[QB][CAP];
    __shared__ unsigned cnt[QB];
    __shared__ float qxs[QB], qys[QB], qzs[QB], sqs[QB];
    __shared__ int sIdx[QB];
    __shared__ float s1s[QB], tAs[QB], tBs[QB];
    __shared__ int T1s[QB], cb1s[QB], T2s[QB], cb2s[QB];
    __shared__ float tAcc[QB];
    __shared__ int refq[QB];
    __shared__ int anyRef;
    __shared__ unsigned order[QB][cK];

    int tid = threadIdx.x;
    int qi = tid >> 5, lane = tid & 31;
    int qbase = blockIdx.x * QB;
    int b = qbase / cS;
    int s0 = qbase % cS;
    const float4* pb = xyzp + (size_t)b * cN;

    if (tid < QB) {
        int si = sidx_g[b * cS + s0 + tid];
        sIdx[tid] = si;
        float x = xyz[(b * 3 + 0) * cN + si];
        float y = xyz[(b * 3 + 1) * cN + si];
        float z = xyz[(b * 3 + 2) * cN + si];
        qxs[tid] = x; qys[tid] = y; qzs[tid] = z;
        sqs[tid] = __fadd_rn(__fadd_rn(__fmul_rn(x, x), __fmul_rn(y, y)), __fmul_rn(z, z));
        cnt[tid] = 0u;
    }
    if (tid == 0) anyRef = 0;
    for (int i = tid; i < QB * 258; i += 256) ((unsigned*)hist)[i] = 0u;
    __syncthreads();

    // ---- sampling: R = max over 32 lanes of (min fast-d over 64 points) >= d_32 ----
    {
        float qx = qxs[qi], qy = qys[qi], qz = qzs[qi], qsq = sqs[qi];
        float dmin = 3.4e38f;
        for (int t = 0; t < 64; ++t) {
            float4 p = pb[lane + 32 * t];
            float dot = fmaf(qx, p.x, fmaf(qy, p.y, qz * p.z));
            float d = fmaf(-2.0f, dot, qsq + p.w);
            dmin = fminf(dmin, d);
        }
        float rmax = dmin;
#pragma unroll
        for (int off = 16; off; off >>= 1)
            rmax = fmaxf(rmax, __shfl_xor(rmax, off, 32));
        if (lane == 0) {
            float R = fmaxf(rmax, 1e-12f);
            float s1 = 254.0f / R;
            s1s[qi] = s1;
            tAs[qi] = qsq * s1;
            tBs[qi] = -2.0f * s1;
        }
    }
    __syncthreads();

    float lqx[QB], lqy[QB], lqz[QB], lS[QB], lA[QB], lB[QB];
#pragma unroll
    for (int q = 0; q < QB; q++) {
        lqx[q] = qxs[q]; lqy[q] = qys[q]; lqz[q] = qzs[q];
        lS[q] = s1s[q]; lA[q] = tAs[q]; lB[q] = tBs[q];
    }

    // ---- pass 1: histogram in t-units; skip atomic when t >= 258 (~95% of pts) ----
    for (int j = 0; j < cN / 256; ++j) {
        float4 p = pb[j * 256 + tid];
#pragma unroll
        for (int q = 0; q < QB; ++q) {
            float dot = fmaf(lqx[q], p.x, fmaf(lqy[q], p.y, lqz[q] * p.z));
            float t = fmaf(dot, lB[q], fmaf(p.w, lS[q], lA[q]));
            if (t < 258.0f) {
                int bin = __float2int_rz(fmaxf(t, 0.0f));
                atomicAdd(&hist[q][bin], 1u);
            }
        }
    }
    __syncthreads();

    selectBin2(hist[qi], lane, cK, &T1s[qi], &cb1s[qi]);
    __syncthreads();
    if (tid < QB) {
        int T1 = T1s[tid];
        int acc = cb1s[tid] + (int)hist[tid][T1] + (int)hist[tid][T1 + 1];
        int nr = (acc > CAP) ? 1 : 0;
        refq[tid] = nr;
        tAcc[tid] = (float)(T1 + 2);            // 1-bin margin covers fast-d rounding
        if (nr) atomicOr(&anyRef, 1);
    }
    __syncthreads();

    // ---- rare refine: sub-bin [T1, T1+2) ----
    if (anyRef) {
        for (int i = tid; i < QB * 258; i += 256) ((unsigned*)hist)[i] = 0u;
        __syncthreads();
        int lT1[QB], lrf[QB];
#pragma unroll
        for (int q = 0; q < QB; q++) { lT1[q] = T1s[q]; lrf[q] = refq[q]; }
        for (int j = 0; j < cN / 256; ++j) {
            float4 p = pb[j * 256 + tid];
#pragma unroll
            for (int q = 0; q < QB; ++q) {
                if (lrf[q]) {
                    float dot = fmaf(lqx[q], p.x, fmaf(lqy[q], p.y, lqz[q] * p.z));
                    float t = fmaf(dot, lB[q], fmaf(p.w, lS[q], lA[q]));
                    float um = fmaxf(t, 0.0f) - (float)lT1[q];
                    if (um >= 0.0f && um < 2.0f) {
                        int sub = min(255, __float2int_rz(um * 128.0f));
                        atomicAdd(&hist[q][sub], 1u);
                    }
                }
            }
        }
        __syncthreads();
        if (refq[qi]) selectBin2(hist[qi], lane, cK - cb1s[qi], &T2s[qi], &cb2s[qi]);
        __syncthreads();
        if (tid < QB && refq[tid])
            tAcc[tid] = (float)T1s[tid] + (float)(T2s[tid] + 2) * 0.0078125f;
        __syncthreads();
    }

    float lsq[QB], lt[QB];
#pragma unroll
    for (int q = 0; q < QB; q++) { lsq[q] = sqs[q]; lt[q] = tAcc[q]; }

    // ---- pass 2: collect candidates (superset of exact top-K), exact keys ----
    for (int j = 0; j < cN / 256; ++j) {
        int n = j * 256 + tid;
        float4 p = pb[n];
#pragma unroll
        for (int q = 0; q < QB; ++q) {
            float dot = fmaf(lqx[q], p.x, fmaf(lqy[q], p.y, lqz[q] * p.z));
            float t = fmaf(dot, lB[q], fmaf(p.w, lS[q], lA[q]));
            if (t < lt[q]) {
                float de = distNp(lqx[q], lqy[q], lqz[q], lsq[q], p);
                unsigned pos = atomicAdd(&cnt[q], 1u);
                if (pos < CAP)
                    cand[q][pos] = ((unsigned long long)keyOf(de) << 32) | (unsigned)n;
            }
        }
    }
    __syncthreads();

    // ---- exact 32-round min-extraction (wave-synchronous, order-invariant) ----
    int m = (int)min(cnt[qi], (unsigned)CAP);
    for (int r = 0; r < cK; ++r) {
        unsigned long long best = ~0ull;
        int bslot = -1;
        for (int i = lane; i < m; i += 32) {
            unsigned long long v = cand[qi][i];
            if (v < best) { best = v; bslot = i; }
        }
#pragma unroll
        for (int off = 16; off; off >>= 1) {
            unsigned long long ov = __shfl_xor(best, off, 32);
            int os = __shfl_xor(bslot, off, 32);
            if (ov < best) { best = ov; bslot = os; }
        }
        if (lane == 0) {
            order[qi][r] = (best != ~0ull) ? (unsigned)(best & 0xFFFFFFFFull) : 0u;
            if (bslot >= 0) cand[qi][bslot] = ~0ull;
        }
    }

    // ---- outputs ----
    {
        int r = lane;
        int s = s0 + qi;
        int n = (int)order[qi][r];
        size_t pos = (size_t)(b * cS + s) * cK + r;
        idxw[pos] = n;
        float px = xyz[(b * 3 + 0) * cN + n];
        float py = xyz[(b * 3 + 1) * cN + n];
        float pz = xyz[(b * 3 + 2) * cN + n];
        outbuf[OUT2_OFF + pos * 3 + 0] = px;
        outbuf[OUT2_OFF + pos * 3 + 1] = py;
        outbuf[OUT2_OFF + pos * 3 + 2] = pz;
        normw[pos * 3 + 0] = __fsub_rn(px, qxs[qi]);
        normw[pos * 3 + 1] = __fsub_rn(py, qys[qi]);
        normw[pos * 3 + 2] = __fsub_rn(pz, qzs[qi]);
        if (r == 0) {
            outbuf[OUT3_OFF + b * cS + s] = (float)sIdx[qi];
            outbuf[(b * 3 + 0) * cS + s] = qxs[qi];
            outbuf[(b * 3 + 1) * cS + s] = qys[qi];
            outbuf[(b * 3 + 2) * cS + s] = qzs[qi];
        }
    }
}

// ---------------- conv0s: stats-only conv0 (no y0 write; partials identical to r8) ----------------
__global__ __launch_bounds__(256) void k_conv0s(const int* __restrict__ idxw,
                                                const float* __restrict__ normw,
                                                const float* __restrict__ ptsT,
                                                const float* __restrict__ w0,
                                                const float* __restrict__ b0,
                                                float2* __restrict__ part0) {
    __shared__ __align__(16) float fAT[67 * 132];
    __shared__ __align__(16) float wT[67 * 68];
    __shared__ float bl[64];
    int tid = threadIdx.x;
    int blk = blockIdx.x;
    int b = blk >> 8;
    int s0 = (blk & 255) << 2;
    size_t posbase = ((size_t)b * cS + s0) * cK;

    for (int l = tid; l < 64 * 67; l += 256) {
        int o = l / 67, c = l - o * 67;
        wT[c * 68 + o] = w0[l];
    }
    if (tid < 64) bl[tid] = b0[tid];
    {
        int r = tid >> 1, half = tid & 1;
        size_t pos = posbase + r;
        int n = idxw[pos];
        const float* pr = ptsT + ((size_t)b * cN + n) * 64 + half * 32;
#pragma unroll
        for (int q = 0; q < 8; q++) {
            float4 v = *(const float4*)(pr + q * 4);
            int c = 3 + half * 32 + q * 4;
            fAT[(c + 0) * 132 + r] = v.x;
            fAT[(c + 1) * 132 + r] = v.y;
            fAT[(c + 2) * 132 + r] = v.z;
            fAT[(c + 3) * 132 + r] = v.w;
        }
        if (half == 0) {
            fAT[0 * 132 + r] = normw[pos * 3 + 0];
            fAT[1 * 132 + r] = normw[pos * 3 + 1];
            fAT[2 * 132 + r] = normw[pos * 3 + 2];
        }
    }
    __syncthreads();

    int ry = tid >> 4, tx = tid & 15;
    float acc[8][4];
#pragma unroll
    for (int i = 0; i < 8; i++)
#pragma unroll
        for (int j = 0; j < 4; j++) acc[i][j] = bl[tx * 4 + j];

    for (int c = 0; c < 67; ++c) {
        const float* fb = fAT + c * 132;
        float4 a0 = *(const float4*)(fb + ry * 8);
        float4 a1 = *(const float4*)(fb + ry * 8 + 4);
        float4 wv = *(const float4*)&wT[c * 68 + tx * 4];
        float av[8] = {a0.x, a0.y, a0.z, a0.w, a1.x, a1.y, a1.z, a1.w};
#pragma unroll
        for (int i = 0; i < 8; i++) {
            acc[i][0] = fmaf(av[i], wv.x, acc[i][0]);
            acc[i][1] = fmaf(av[i], wv.y, acc[i][1]);
            acc[i][2] = fmaf(av[i], wv.z, acc[i][2]);
            acc[i][3] = fmaf(av[i], wv.w, acc[i][3]);
        }
    }
    __syncthreads();   // done with wT; overlay partial buffers

    float* ps = wT;
    float* pq = wT + 16 * 64;
#pragma unroll
    for (int j = 0; j < 4; j++) {
        float s = 0.f, q = 0.f;
#pragma unroll
        for (int i = 0; i < 8; i++) { float v = acc[i][j]; s += v; q += v * v; }
        ps[ry * 64 + tx * 4 + j] = s;
        pq[ry * 64 + tx * 4 + j] = q;
    }
    __syncthreads();
    if (tid < 64) {
        float s = 0.f, q = 0.f;
        for (int t = 0; t < 16; t++) { s += ps[t * 64 + tid]; q += pq[t * 64 + tid]; }
        part0[(size_t)blk * 64 + tid] = make_float2(s, q);
    }
}

// ---------------- conv01: fused gather+GEMM0+BN0+ReLU+GEMM1 -> y1 + p1 ----------------
// GEMM0 identical accumulation to conv0s (bitwise-same y0); GEMM1 per-element order
// = c ascending = bitwise-same as r8 conv1. LDS: fU union (34.8KB) + wbuf (18.2KB) -> 3 blk/CU.
__global__ __launch_bounds__(256) void k_conv01(const int* __restrict__ idxw,
                                                const float* __restrict__ normw,
                                                const float* __restrict__ ptsT,
                                                const float* __restrict__ w0,
                                                const float* __restrict__ b0,
                                                const float2* __restrict__ bn0,
                                                const float* __restrict__ w1,
                                                const float* __restrict__ b1,
                                                float* __restrict__ y1,
                                                float2* __restrict__ part1) {
    __shared__ __align__(16) float fU[8704];       // fAT 67x128 (c-major) -> fA2 128x68 (row-major)
    __shared__ __align__(16) float wbuf[67 * 68];  // wT0 then wT1, c-major [c][o]
    __shared__ float bl0[64], al[64], sl[64], bl1[64];
    int tid = threadIdx.x;
    int blk = blockIdx.x;
    int b = blk >> 8;
    int s0 = (blk & 255) << 2;
    size_t posbase = ((size_t)b * cS + s0) * cK;

    for (int l = tid; l < 64 * 67; l += 256) {
        int o = l / 67, c = l - o * 67;
        wbuf[c * 68 + o] = w0[l];
    }
    if (tid < 64) {
        bl0[tid] = b0[tid];
        float2 t = bn0[tid];
        al[tid] = t.x; sl[tid] = t.y;
        bl1[tid] = b1[tid];
    }
    {
        int r = tid >> 1, half = tid & 1;
        size_t pos = posbase + r;
        int n = idxw[pos];
        const float* pr = ptsT + ((size_t)b * cN + n) * 64 + half * 32;
#pragma unroll
        for (int q = 0; q < 8; q++) {
            float4 v = *(const float4*)(pr + q * 4);
            int c = 3 + half * 32 + q * 4;
            fU[(c + 0) * 128 + r] = v.x;
            fU[(c + 1) * 128 + r] = v.y;
            fU[(c + 2) * 128 + r] = v.z;
            fU[(c + 3) * 128 + r] = v.w;
        }
        if (half == 0) {
            fU[0 * 128 + r] = normw[pos * 3 + 0];
            fU[1 * 128 + r] = normw[pos * 3 + 1];
            fU[2 * 128 + r] = normw[pos * 3 + 2];
        }
    }
    __syncthreads();

    int ry = tid >> 4, tx = tid & 15;
    // ---- GEMM0 (identical accumulation order to conv0s) ----
    float acc[8][4];
#pragma unroll
    for (int i = 0; i < 8; i++)
#pragma unroll
        for (int j = 0; j < 4; j++) acc[i][j] = bl0[tx * 4 + j];

    for (int c = 0; c < 67; ++c) {
        const float* fb = fU + c * 128;
        float4 a0 = *(const float4*)(fb + ry * 8);
        float4 a1 = *(const float4*)(fb + ry * 8 + 4);
        float4 wv = *(const float4*)&wbuf[c * 68 + tx * 4];
        float av[8] = {a0.x, a0.y, a0.z, a0.w, a1.x, a1.y, a1.z, a1.w};
#pragma unroll
        for (int i = 0; i < 8; i++) {
            acc[i][0] = fmaf(av[i], wv.x, acc[i][0]);
            acc[i][1] = fmaf(av[i], wv.y, acc[i][1]);
            acc[i][2] = fmaf(av[i], wv.z, acc[i][2]);
            acc[i][3] = fmaf(av[i], wv.w, acc[i][3]);
        }
    }
    __syncthreads();   // all fU/wbuf reads complete

    // ---- reload weights (w1) and stage relu(bn0(y0)) row-major into fU ----
    for (int l = tid; l < 64 * 64; l += 256) {
        int o = l >> 6, c = l & 63;
        wbuf[c * 68 + o] = w1[l];
    }
#pragma unroll
    for (int i = 0; i < 8; i++) {
        int row = ry * 8 + i;
        float4 v;
        v.x = fmaxf(fmaf(acc[i][0], al[tx * 4 + 0], sl[tx * 4 + 0]), 0.0f);
        v.y = fmaxf(fmaf(acc[i][1], al[tx * 4 + 1], sl[tx * 4 + 1]), 0.0f);
        v.z = fmaxf(fmaf(acc[i][2], al[tx * 4 + 2], sl[tx * 4 + 2]), 0.0f);
        v.w = fmaxf(fmaf(acc[i][3], al[tx * 4 + 3], sl[tx * 4 + 3]), 0.0f);
        *(float4*)&fU[row * 68 + tx * 4] = v;
    }
    __syncthreads();

    // ---- GEMM1 (per-element c-ascending order == r8 conv1, bitwise identical) ----
    float acc1[8][4];
#pragma unroll
    for (int i = 0; i < 8; i++)
#pragma unroll
        for (int j = 0; j < 4; j++) acc1[i][j] = bl1[tx * 4 + j];

    for (int c4 = 0; c4 < 16; ++c4) {
        float4 wv[4];
#pragma unroll
        for (int cc = 0; cc < 4; cc++)
            wv[cc] = *(const float4*)&wbuf[(c4 * 4 + cc) * 68 + tx * 4];
#pragma unroll
        for (int i = 0; i < 8; i++) {
            float4 a = *(const float4*)&fU[(ry * 8 + i) * 68 + c4 * 4];
            acc1[i][0] = fmaf(a.x, wv[0].x, acc1[i][0]);
            acc1[i][1] = fmaf(a.x, wv[0].y, acc1[i][1]);
            acc1[i][2] = fmaf(a.x, wv[0].z, acc1[i][2]);
            acc1[i][3] = fmaf(a.x, wv[0].w, acc1[i][3]);
            acc1[i][0] = fmaf(a.y, wv[1].x, acc1[i][0]);
            acc1[i][1] = fmaf(a.y, wv[1].y, acc1[i][1]);
            acc1[i][2] = fmaf(a.y, wv[1].z, acc1[i][2]);
            acc1[i][3] = fmaf(a.y, wv[1].w, acc1[i][3]);
            acc1[i][0] = fmaf(a.z, wv[2].x, acc1[i][0]);
            acc1[i][1] = fmaf(a.z, wv[2].y, acc1[i][1]);
            acc1[i][2] = fmaf(a.z, wv[2].z, acc1[i][2]);
            acc1[i][3] = fmaf(a.z, wv[2].w, acc1[i][3]);
            acc1[i][0] = fmaf(a.w, wv[3].x, acc1[i][0]);
            acc1[i][1] = fmaf(a.w, wv[3].y, acc1[i][1]);
            acc1[i][2] = fmaf(a.w, wv[3].z, acc1[i][2]);
            acc1[i][3] = fmaf(a.w, wv[3].w, acc1[i][3]);
        }
    }
#pragma unroll
    for (int i = 0; i < 8; i++) {
        float4 o4 = make_float4(acc1[i][0], acc1[i][1], acc1[i][2], acc1[i][3]);
        *(float4*)(y1 + (posbase + ry * 8 + i) * 64 + tx * 4) = o4;
    }
    __syncthreads();   // done with wbuf; overlay partial buffers

    float* ps = wbuf;
    float* pq = wbuf + 16 * 64;
#pragma unroll
    for (int j = 0; j < 4; j++) {
        float s = 0.f, q = 0.f;
#pragma unroll
        for (int i = 0; i < 8; i++) { float v = acc1[i][j]; s += v; q += v * v; }
        ps[ry * 64 + tx * 4 + j] = s;
        pq[ry * 64 + tx * 4 + j] = q;
    }
    __syncthreads();
    if (tid < 64) {
        float s = 0.f, q = 0.f;
        for (int t = 0; t < 16; t++) { s += ps[t * 64 + tid]; q += pq[t * 64 + tid]; }
        part1[(size_t)blk * 64 + tid] = make_float2(s, q);
    }
}

// ---------------- conv2: 128 pos/block, 8x8 tile, both operands c-major ----------------
__global__ __launch_bounds__(256) void k_conv2(const float* __restrict__ y1,
                                               const float2* __restrict__ bn1,
                                               const float* __restrict__ w2,
                                               const float* __restrict__ b2,
                                               float* __restrict__ mx,
                                               float* __restrict__ mn,
                                               float2* __restrict__ part2) {
    __shared__ __align__(16) float fAT[64 * 132];
    __shared__ __align__(16) float wT[64 * 132];
    __shared__ float al[64], sl[64], bl[128];
    int tid = threadIdx.x;
    int blk = blockIdx.x;
    int b = blk >> 8;
    int s0 = (blk & 255) << 2;
    size_t posbase = ((size_t)b * cS + s0) * cK;

    if (tid < 64) { float2 t = bn1[tid]; al[tid] = t.x; sl[tid] = t.y; }
    if (tid < 128) bl[tid] = b2[tid];
    __syncthreads();

    {
        int r = tid >> 1, half = tid & 1;
        const float* yr = y1 + (posbase + r) * 64 + half * 32;
#pragma unroll
        for (int q = 0; q < 8; q++) {
            float4 v = *(const float4*)(yr + q * 4);
            int c = half * 32 + q * 4;
            v.x = fmaxf(fmaf(v.x, al[c + 0], sl[c + 0]), 0.0f);
            v.y = fmaxf(fmaf(v.y, al[c + 1], sl[c + 1]), 0.0f);
            v.z = fmaxf(fmaf(v.z, al[c + 2], sl[c + 2]), 0.0f);
            v.w = fmaxf(fmaf(v.w, al[c + 3], sl[c + 3]), 0.0f);
            fAT[(c + 0) * 132 + r] = v.x;
            fAT[(c + 1) * 132 + r] = v.y;
            fAT[(c + 2) * 132 + r] = v.z;
            fAT[(c + 3) * 132 + r] = v.w;
        }
    }
    for (int l = tid; l < 128 * 64; l += 256) {
        int o = l >> 6, c = l & 63;
        wT[c * 132 + o] = w2[l];
    }
    __syncthreads();

    int ry = tid >> 4, tx = tid & 15;
    float acc[8][8];
#pragma unroll
    for (int i = 0; i < 8; i++) {
#pragma unroll
        for (int j = 0; j < 4; j++) acc[i][j] = bl[tx * 4 + j];
#pragma unroll
        for (int j = 4; j < 8; j++) acc[i][j] = bl[64 + tx * 4 + (j - 4)];
    }

    for (int c = 0; c < 64; ++c) {
        const float* fb = fAT + c * 132;
        const float* wb = wT + c * 132;
        float4 a0 = *(const float4*)(fb + ry * 8);
        float4 a1 = *(const float4*)(fb + ry * 8 + 4);
        float4 w0v = *(const float4*)(wb + tx * 4);
        float4 w1v = *(const float4*)(wb + 64 + tx * 4);
        float av[8] = {a0.x, a0.y, a0.z, a0.w, a1.x, a1.y, a1.z, a1.w};
        float wv[8] = {w0v.x, w0v.y, w0v.z, w0v.w, w1v.x, w1v.y, w1v.z, w1v.w};
#pragma unroll
        for (int i = 0; i < 8; i++)
#pragma unroll
            for (int j = 0; j < 8; j++)
                acc[i][j] = fmaf(av[i], wv[j], acc[i][j]);
    }
    __syncthreads();

    float* ps  = wT;
    float* pq  = wT + 16 * 128;
    float* pmx = wT + 32 * 128;
    float* pmn = wT + 48 * 128;
#pragma unroll
    for (int j = 0; j < 8; j++) {
        int o = (j < 4) ? (tx * 4 + j) : (64 + tx * 4 + (j - 4));
        float s = 0.f, q = 0.f;
        float mv = -3.402823466e+38f, nv = 3.402823466e+38f;
#pragma unroll
        for (int i = 0; i < 8; i++) {
            float v = acc[i][j];
            s += v; q += v * v;
            mv = fmaxf(mv, v); nv = fminf(nv, v);
        }
        ps[ry * 128 + o] = s;
        pq[ry * 128 + o] = q;
        pmx[ry * 128 + o] = mv;
        pmn[ry * 128 + o] = nv;
    }
    __syncthreads();
    if (tid < 128) {
        float s = 0.f, q = 0.f;
        for (int t = 0; t < 16; t++) { s += ps[t * 128 + tid]; q += pq[t * 128 + tid]; }
        part2[(size_t)blk * 128 + tid] = make_float2(s, q);
    }
    for (int e = tid; e < 512; e += 256) {
        int sg = e >> 7, o = e & 127;
        float mv = -3.402823466e+38f, nv = 3.402823466e+38f;
        for (int t = sg * 4; t < sg * 4 + 4; ++t) {
            mv = fmaxf(mv, pmx[t * 128 + o]);
            nv = fminf(nv, pmn[t * 128 + o]);
        }
        int s = s0 + sg;
        mx[((size_t)b * cS + s) * 128 + o] = mv;
        mn[((size_t)b * cS + s) * 128 + o] = nv;
    }
}

// ---------------- BN finalize (float2 partials, f64 accumulate) ----------------
__global__ __launch_bounds__(256) void k_fin(const float2* __restrict__ part, int nblk,
                                             int oc,
                                             const float* __restrict__ g,
                                             const float* __restrict__ be,
                                             float2* __restrict__ bnout) {
    __shared__ double rs[256], rq[256];
    int o = blockIdx.x;
    int tid = threadIdx.x;
    double s = 0.0, q = 0.0;
    for (int i = tid; i < nblk; i += 256) {
        float2 p = part[(size_t)i * oc + o];
        s += (double)p.x;
        q += (double)p.y;
    }
    rs[tid] = s; rq[tid] = q;
    __syncthreads();
    for (int off = 128; off; off >>= 1) {
        if (tid < off) { rs[tid] += rs[tid + off]; rq[tid] += rq[tid + off]; }
        __syncthreads();
    }
    if (tid == 0) {
        double cntv = (double)PTOT;
        double mu = rs[0] / cntv;
        double var = rq[0] / cntv - mu * mu;
        if (var < 0.0) var = 0.0;
        float a = (float)((double)g[o] / sqrt(var + 1e-5));
        float sh = (float)((double)be[o] - mu * (double)a);
        bnout[o] = make_float2(a, sh);
    }
}

// ---------------- final: BN2(max_k y2)+ReLU -> new_points [B,128,S] ----------------
__global__ __launch_bounds__(256) void k_final(const float* __restrict__ mx,
                                               const float* __restrict__ mn,
                                               const float2* __restrict__ bn2,
                                               float* __restrict__ out1) {
    int i = blockIdx.x * 256 + threadIdx.x;
    int b = i >> 17;
    int r = i & ((1 << 17) - 1);
    int o = r >> 10;
    int s = r & 1023;
    float2 t = bn2[o];
    size_t idx = ((size_t)b * cS + s) * 128 + o;
    float M = (t.x >= 0.0f) ? mx[idx] : mn[idx];
    out1[i] = fmaxf(t.x * M + t.y, 0.0f);
}

// ---------------- launcher ----------------
extern "C" void kernel_launch(void* const* d_in, const int* in_sizes, int n_in,
                              void* d_out, int out_size, void* d_ws, size_t ws_size,
                              hipStream_t stream) {
    (void)in_sizes; (void)n_in; (void)out_size;
    const float* xyz = (const float*)d_in[0];
    const float* pts = (const float*)d_in[1];
    const int* sidx  = (const int*)d_in[2];
    const float* w0  = (const float*)d_in[3];
    const float* b0  = (const float*)d_in[4];
    const float* g0  = (const float*)d_in[5];
    const float* be0 = (const float*)d_in[6];
    const float* w1  = (const float*)d_in[7];
    const float* b1  = (const float*)d_in[8];
    const float* g1  = (const float*)d_in[9];
    const float* be1 = (const float*)d_in[10];
    const float* w2  = (const float*)d_in[11];
    const float* b2  = (const float*)d_in[12];
    const float* g2  = (const float*)d_in[13];
    const float* be2 = (const float*)d_in[14];
    float* out = (float*)d_out;
    char* ws = (char*)d_ws;
    if (ws_size < WS_END) return;

    float* ptsT  = (float*)(ws + WS_PTS);
    float4* xyzp = (float4*)(ws + WS_XYZP);
    int* idxw    = (int*)(ws + WS_IDX);
    float* normw = (float*)(ws + WS_NORM);
    float* y1    = (float*)(ws + WS_Y1);
    float* mx    = (float*)(ws + WS_MX);
    float* mn    = (float*)(ws + WS_MN);
    float2* p0   = (float2*)(ws + WS_P0);
    float2* p1   = (float2*)(ws + WS_P1);
    float2* p2   = (float2*)(ws + WS_P2);
    float2* bnb  = (float2*)(ws + WS_BN);

    hipLaunchKernelGGL(k_prep, dim3(2048 + cB * cN / 256), dim3(256), 0, stream,
                       pts, xyz, ptsT, xyzp);
    hipLaunchKernelGGL(k_knn, dim3(cB * cS / QB), dim3(256), 0, stream,
                       xyz, sidx, xyzp, idxw, normw, out);
    hipLaunchKernelGGL(k_conv0s, dim3(NBLK2), dim3(256), 0, stream,
                       idxw, normw, ptsT, w0, b0, p0);
    hipLaunchKernelGGL(k_fin, dim3(64), dim3(256), 0, stream, p0, NBLK2, 64, g0, be0, bnb);
    hipLaunchKernelGGL(k_conv01, dim3(NBLK2), dim3(256), 0, stream,
                       idxw, normw, ptsT, w0, b0, bnb, w1, b1, y1, p1);
    hipLaunchKernelGGL(k_fin, dim3(64), dim3(256), 0, stream, p1, NBLK2, 64, g1, be1, bnb + 128);
    hipLaunchKernelGGL(k_conv2, dim3(NBLK2), dim3(256), 0, stream,
                       y1, bnb + 128, w2, b2, mx, mn, p2);
    hipLaunchKernelGGL(k_fin, dim3(128), dim3(256), 0, stream, p2, NBLK2, 128, g2, be2, bnb + 256);
    hipLaunchKernelGGL(k_final, dim3(cB * cO2 * cS / 256), dim3(256), 0, stream,
                       mx, mn, bnb + 256, out + OUT1_OFF);
}

// Round 10
// 377.669 us; speedup vs baseline: 1.0790x; 1.0790x over previous
//
#include <hip/hip_runtime.h>

// ---------------- problem constants ----------------
constexpr int cB = 8, cN = 16384, cS = 1024, cK = 32, cD = 64;
constexpr int cO2 = 128;
constexpr int PTOT = cB * cS * cK;              // 262144 positions
constexpr int NBLK2 = PTOT / 128;               // 2048 conv blocks (128 positions each)

// output offsets (floats)
constexpr int OUT1_OFF = cB * 3 * cS;                    // 24576
constexpr int OUT2_OFF = OUT1_OFF + cB * cO2 * cS;       // 1073152
constexpr int OUT3_OFF = OUT2_OFF + cB * cS * cK * 3;    // 1859584

// workspace offsets (bytes)
constexpr size_t WS_PTS  = 0;                                         // [B][N][64] f32
constexpr size_t WS_XYZP = WS_PTS  + (size_t)cB * cN * cD * 4;        // [B][N] float4
constexpr size_t WS_IDX  = WS_XYZP + (size_t)cB * cN * 16;            // [P] int
constexpr size_t WS_NORM = WS_IDX  + (size_t)PTOT * 4;                // [P][3] f32
constexpr size_t WS_Y0   = WS_NORM + (size_t)PTOT * 3 * 4;            // [P][64] f32
constexpr size_t WS_Y1   = WS_Y0   + (size_t)PTOT * 64 * 4;          // [P][64] f32
constexpr size_t WS_MX   = WS_Y1   + (size_t)PTOT * 64 * 4;          // [B*S][128] f32
constexpr size_t WS_MN   = WS_MX   + (size_t)cB * cS * cO2 * 4;
constexpr size_t WS_P0   = WS_MN   + (size_t)cB * cS * cO2 * 4;      // [2048][64] float2
constexpr size_t WS_P1   = WS_P0   + (size_t)NBLK2 * 64 * 8;
constexpr size_t WS_P2   = WS_P1   + (size_t)NBLK2 * 64 * 8;         // [2048][128] float2
constexpr size_t WS_BN   = WS_P2   + (size_t)NBLK2 * 128 * 8;        // 3*128 float2
constexpr size_t WS_END  = WS_BN   + 3 * 128 * 2 * 4;

// ---------------- helpers ----------------
__device__ __forceinline__ unsigned keyOf(float d) {
    unsigned u = __float_as_uint(d);
    return u ^ ((unsigned)((int)u >> 31) | 0x80000000u);
}
// numpy-order, no-FMA distance: (ssq_q + ssq_p) - 2*((qx*px + qy*py) + qz*pz)
__device__ __forceinline__ float distNp(float qx, float qy, float qz, float sq, float4 p) {
    float m0 = __fmul_rn(qx, p.x);
    float m1 = __fmul_rn(qy, p.y);
    float m2 = __fmul_rn(qz, p.z);
    float dt = __fadd_rn(__fadd_rn(m0, m1), m2);
    return __fsub_rn(__fadd_rn(sq, p.w), __fmul_rn(2.0f, dt));
}

// ---------------- prep: transpose points + pack xyz (merged launch) ----------------
__global__ __launch_bounds__(256) void k_prep(const float* __restrict__ pts,
                                              const float* __restrict__ xyz,
                                              float* __restrict__ ptsT,
                                              float4* __restrict__ xyzp) {
    __shared__ float tile[64][65];
    int blk = blockIdx.x;
    int tid = threadIdx.x;
    if (blk < 2048) {
        int b = blk >> 8;
        int n0 = (blk & 255) * 64;
        for (int it = 0; it < 16; ++it) {
            int l = it * 256 + tid;
            int c = l >> 6, nn = l & 63;
            tile[nn][c] = pts[((size_t)b * 64 + c) * cN + n0 + nn];
        }
        __syncthreads();
        for (int it = 0; it < 16; ++it) {
            int l = it * 256 + tid;
            int nn = l >> 6, c = l & 63;
            ptsT[((size_t)(b * cN + n0 + nn)) * 64 + c] = tile[nn][c];
        }
    } else {
        int i = (blk - 2048) * 256 + tid;   // < B*N
        int b = i >> 14, n = i & (cN - 1);
        float x = xyz[(b * 3 + 0) * cN + n];
        float y = xyz[(b * 3 + 1) * cN + n];
        float z = xyz[(b * 3 + 2) * cN + n];
        float sq = __fadd_rn(__fadd_rn(__fmul_rn(x, x), __fmul_rn(y, y)), __fmul_rn(z, z));
        xyzp[i] = make_float4(x, y, z, sq);
    }
}

// ---------------- kNN (r3-proven): tight-R sampling + dense hist + dense collect ----------------
#define QB 8
#define CAP 256

__device__ __forceinline__ void selectBin2(const unsigned* __restrict__ h, int lane,
                                           int target, int* Tout, int* cbOut) {
    int base = lane * 8;
    unsigned hh[8];
    unsigned c8 = 0;
#pragma unroll
    for (int i = 0; i < 8; i++) { hh[i] = h[base + i]; c8 += hh[i]; }
    unsigned incl = c8;
#pragma unroll
    for (int off = 1; off < 32; off <<= 1) {
        unsigned t = __shfl_up(incl, (unsigned)off, 32);
        if (lane >= off) incl += t;
    }
    int excl = (int)(incl - c8);
    if (excl < target && target <= (int)incl) {
        int c = excl;
#pragma unroll
        for (int i = 0; i < 8; i++) {
            int nc = c + (int)hh[i];
            if (c < target && target <= nc) { *Tout = base + i; *cbOut = c; }
            c = nc;
        }
    }
}

__global__ __launch_bounds__(256, 4) void k_knn(const float* __restrict__ xyz,
                                                const int* __restrict__ sidx_g,
                                                const float4* __restrict__ xyzp,
                                                int* __restrict__ idxw,
                                                float* __restrict__ normw,
                                                float* __restrict__ outbuf) {
    __shared__ unsigned hist[QB][258];
    __shared__ unsigned long long cand[QB][CAP];
    __shared__ unsigned cnt[QB];
    __shared__ float qxs[QB], qys[QB], qzs[QB], sqs[QB];
    __shared__ int sIdx[QB];
    __shared__ float s1s[QB], tAs[QB], tBs[QB];
    __shared__ int T1s[QB], cb1s[QB], T2s[QB], cb2s[QB];
    __shared__ float tAcc[QB];
    __shared__ int refq[QB];
    __shared__ int anyRef;
    __shared__ unsigned order[QB][cK];

    int tid = threadIdx.x;
    int qi = tid >> 5, lane = tid & 31;
    int qbase = blockIdx.x * QB;
    int b = qbase / cS;
    int s0 = qbase % cS;
    const float4* pb = xyzp + (size_t)b * cN;

    if (tid < QB) {
        int si = sidx_g[b * cS + s0 + tid];
        sIdx[tid] = si;
        float x = xyz[(b * 3 + 0) * cN + si];
        float y = xyz[(b * 3 + 1) * cN + si];
        float z = xyz[(b * 3 + 2) * cN + si];
        qxs[tid] = x; qys[tid] = y; qzs[tid] = z;
        sqs[tid] = __fadd_rn(__fadd_rn(__fmul_rn(x, x), __fmul_rn(y, y)), __fmul_rn(z, z));
        cnt[tid] = 0u;
    }
    if (tid == 0) anyRef = 0;
    for (int i = tid; i < QB * 258; i += 256) ((unsigned*)hist)[i] = 0u;
    __syncthreads();

    // ---- sampling: R = max over 32 lanes of (min fast-d over 64 points) >= d_32 ----
    {
        float qx = qxs[qi], qy = qys[qi], qz = qzs[qi], qsq = sqs[qi];
        float dmin = 3.4e38f;
        for (int t = 0; t < 64; ++t) {
            float4 p = pb[lane + 32 * t];
            float dot = fmaf(qx, p.x, fmaf(qy, p.y, qz * p.z));
            float d = fmaf(-2.0f, dot, qsq + p.w);
            dmin = fminf(dmin, d);
        }
        float rmax = dmin;
#pragma unroll
        for (int off = 16; off; off >>= 1)
            rmax = fmaxf(rmax, __shfl_xor(rmax, off, 32));
        if (lane == 0) {
            float R = fmaxf(rmax, 1e-12f);
            float s1 = 254.0f / R;
            s1s[qi] = s1;
            tAs[qi] = qsq * s1;
            tBs[qi] = -2.0f * s1;
        }
    }
    __syncthreads();

    float lqx[QB], lqy[QB], lqz[QB], lS[QB], lA[QB], lB[QB];
#pragma unroll
    for (int q = 0; q < QB; q++) {
        lqx[q] = qxs[q]; lqy[q] = qys[q]; lqz[q] = qzs[q];
        lS[q] = s1s[q]; lA[q] = tAs[q]; lB[q] = tBs[q];
    }

    // ---- pass 1: histogram in t-units; skip atomic when t >= 258 (~95% of pts) ----
    for (int j = 0; j < cN / 256; ++j) {
        float4 p = pb[j * 256 + tid];
#pragma unroll
        for (int q = 0; q < QB; ++q) {
            float dot = fmaf(lqx[q], p.x, fmaf(lqy[q], p.y, lqz[q] * p.z));
            float t = fmaf(dot, lB[q], fmaf(p.w, lS[q], lA[q]));
            if (t < 258.0f) {
                int bin = __float2int_rz(fmaxf(t, 0.0f));
                atomicAdd(&hist[q][bin], 1u);
            }
        }
    }
    __syncthreads();

    selectBin2(hist[qi], lane, cK, &T1s[qi], &cb1s[qi]);
    __syncthreads();
    if (tid < QB) {
        int T1 = T1s[tid];
        int acc = cb1s[tid] + (int)hist[tid][T1] + (int)hist[tid][T1 + 1];
        int nr = (acc > CAP) ? 1 : 0;
        refq[tid] = nr;
        tAcc[tid] = (float)(T1 + 2);            // 1-bin margin covers fast-d rounding
        if (nr) atomicOr(&anyRef, 1);
    }
    __syncthreads();

    // ---- rare refine: sub-bin [T1, T1+2) ----
    if (anyRef) {
        for (int i = tid; i < QB * 258; i += 256) ((unsigned*)hist)[i] = 0u;
        __syncthreads();
        int lT1[QB], lrf[QB];
#pragma unroll
        for (int q = 0; q < QB; q++) { lT1[q] = T1s[q]; lrf[q] = refq[q]; }
        for (int j = 0; j < cN / 256; ++j) {
            float4 p = pb[j * 256 + tid];
#pragma unroll
            for (int q = 0; q < QB; ++q) {
                if (lrf[q]) {
                    float dot = fmaf(lqx[q], p.x, fmaf(lqy[q], p.y, lqz[q] * p.z));
                    float t = fmaf(dot, lB[q], fmaf(p.w, lS[q], lA[q]));
                    float um = fmaxf(t, 0.0f) - (float)lT1[q];
                    if (um >= 0.0f && um < 2.0f) {
                        int sub = min(255, __float2int_rz(um * 128.0f));
                        atomicAdd(&hist[q][sub], 1u);
                    }
                }
            }
        }
        __syncthreads();
        if (refq[qi]) selectBin2(hist[qi], lane, cK - cb1s[qi], &T2s[qi], &cb2s[qi]);
        __syncthreads();
        if (tid < QB && refq[tid])
            tAcc[tid] = (float)T1s[tid] + (float)(T2s[tid] + 2) * 0.0078125f;
        __syncthreads();
    }

    float lsq[QB], lt[QB];
#pragma unroll
    for (int q = 0; q < QB; q++) { lsq[q] = sqs[q]; lt[q] = tAcc[q]; }

    // ---- pass 2: collect candidates (superset of exact top-K), exact keys ----
    for (int j = 0; j < cN / 256; ++j) {
        int n = j * 256 + tid;
        float4 p = pb[n];
#pragma unroll
        for (int q = 0; q < QB; ++q) {
            float dot = fmaf(lqx[q], p.x, fmaf(lqy[q], p.y, lqz[q] * p.z));
            float t = fmaf(dot, lB[q], fmaf(p.w, lS[q], lA[q]));
            if (t < lt[q]) {
                float de = distNp(lqx[q], lqy[q], lqz[q], lsq[q], p);
                unsigned pos = atomicAdd(&cnt[q], 1u);
                if (pos < CAP)
                    cand[q][pos] = ((unsigned long long)keyOf(de) << 32) | (unsigned)n;
            }
        }
    }
    __syncthreads();

    // ---- exact 32-round min-extraction (wave-synchronous, order-invariant) ----
    int m = (int)min(cnt[qi], (unsigned)CAP);
    for (int r = 0; r < cK; ++r) {
        unsigned long long best = ~0ull;
        int bslot = -1;
        for (int i = lane; i < m; i += 32) {
            unsigned long long v = cand[qi][i];
            if (v < best) { best = v; bslot = i; }
        }
#pragma unroll
        for (int off = 16; off; off >>= 1) {
            unsigned long long ov = __shfl_xor(best, off, 32);
            int os = __shfl_xor(bslot, off, 32);
            if (ov < best) { best = ov; bslot = os; }
        }
        if (lane == 0) {
            order[qi][r] = (best != ~0ull) ? (unsigned)(best & 0xFFFFFFFFull) : 0u;
            if (bslot >= 0) cand[qi][bslot] = ~0ull;
        }
    }

    // ---- outputs ----
    {
        int r = lane;
        int s = s0 + qi;
        int n = (int)order[qi][r];
        size_t pos = (size_t)(b * cS + s) * cK + r;
        idxw[pos] = n;
        float px = xyz[(b * 3 + 0) * cN + n];
        float py = xyz[(b * 3 + 1) * cN + n];
        float pz = xyz[(b * 3 + 2) * cN + n];
        outbuf[OUT2_OFF + pos * 3 + 0] = px;
        outbuf[OUT2_OFF + pos * 3 + 1] = py;
        outbuf[OUT2_OFF + pos * 3 + 2] = pz;
        normw[pos * 3 + 0] = __fsub_rn(px, qxs[qi]);
        normw[pos * 3 + 1] = __fsub_rn(py, qys[qi]);
        normw[pos * 3 + 2] = __fsub_rn(pz, qzs[qi]);
        if (r == 0) {
            outbuf[OUT3_OFF + b * cS + s] = (float)sIdx[qi];
            outbuf[(b * 3 + 0) * cS + s] = qxs[qi];
            outbuf[(b * 3 + 1) * cS + s] = qys[qi];
            outbuf[(b * 3 + 2) * cS + s] = qzs[qi];
        }
    }
}

// ---------------- conv0: 67 -> 64, 128 pos/block, 8x4 tile, c-major ----------------
__global__ __launch_bounds__(256) void k_conv0(const int* __restrict__ idxw,
                                               const float* __restrict__ normw,
                                               const float* __restrict__ ptsT,
                                               const float* __restrict__ w0,
                                               const float* __restrict__ b0,
                                               float* __restrict__ y0,
                                               float2* __restrict__ part0) {
    __shared__ __align__(16) float fAT[67 * 132];
    __shared__ __align__(16) float wT[67 * 68];
    __shared__ float bl[64];
    int tid = threadIdx.x;
    int blk = blockIdx.x;
    int b = blk >> 8;
    int s0 = (blk & 255) << 2;
    size_t posbase = ((size_t)b * cS + s0) * cK;

    for (int l = tid; l < 64 * 67; l += 256) {
        int o = l / 67, c = l - o * 67;
        wT[c * 68 + o] = w0[l];
    }
    if (tid < 64) bl[tid] = b0[tid];
    {
        int r = tid >> 1, half = tid & 1;
        size_t pos = posbase + r;
        int n = idxw[pos];
        const float* pr = ptsT + ((size_t)b * cN + n) * 64 + half * 32;
#pragma unroll
        for (int q = 0; q < 8; q++) {
            float4 v = *(const float4*)(pr + q * 4);
            int c = 3 + half * 32 + q * 4;
            fAT[(c + 0) * 132 + r] = v.x;
            fAT[(c + 1) * 132 + r] = v.y;
            fAT[(c + 2) * 132 + r] = v.z;
            fAT[(c + 3) * 132 + r] = v.w;
        }
        if (half == 0) {
            fAT[0 * 132 + r] = normw[pos * 3 + 0];
            fAT[1 * 132 + r] = normw[pos * 3 + 1];
            fAT[2 * 132 + r] = normw[pos * 3 + 2];
        }
    }
    __syncthreads();

    int ry = tid >> 4, tx = tid & 15;
    float acc[8][4];
#pragma unroll
    for (int i = 0; i < 8; i++)
#pragma unroll
        for (int j = 0; j < 4; j++) acc[i][j] = bl[tx * 4 + j];

    for (int c = 0; c < 67; ++c) {
        const float* fb = fAT + c * 132;
        float4 a0 = *(const float4*)(fb + ry * 8);
        float4 a1 = *(const float4*)(fb + ry * 8 + 4);
        float4 wv = *(const float4*)&wT[c * 68 + tx * 4];
        float av[8] = {a0.x, a0.y, a0.z, a0.w, a1.x, a1.y, a1.z, a1.w};
#pragma unroll
        for (int i = 0; i < 8; i++) {
            acc[i][0] = fmaf(av[i], wv.x, acc[i][0]);
            acc[i][1] = fmaf(av[i], wv.y, acc[i][1]);
            acc[i][2] = fmaf(av[i], wv.z, acc[i][2]);
            acc[i][3] = fmaf(av[i], wv.w, acc[i][3]);
        }
    }
#pragma unroll
    for (int i = 0; i < 8; i++) {
        float4 o4 = make_float4(acc[i][0], acc[i][1], acc[i][2], acc[i][3]);
        *(float4*)(y0 + (posbase + ry * 8 + i) * 64 + tx * 4) = o4;
    }
    __syncthreads();

    float* ps = wT;
    float* pq = wT + 16 * 64;
#pragma unroll
    for (int j = 0; j < 4; j++) {
        float s = 0.f, q = 0.f;
#pragma unroll
        for (int i = 0; i < 8; i++) { float v = acc[i][j]; s += v; q += v * v; }
        ps[ry * 64 + tx * 4 + j] = s;
        pq[ry * 64 + tx * 4 + j] = q;
    }
    __syncthreads();
    if (tid < 64) {
        float s = 0.f, q = 0.f;
        for (int t = 0; t < 16; t++) { s += ps[t * 64 + tid]; q += pq[t * 64 + tid]; }
        part0[(size_t)blk * 64 + tid] = make_float2(s, q);
    }
}

// ---------------- conv1: BN0+ReLU fused load, 64 -> 64, 128 pos/block ----------------
__global__ __launch_bounds__(256) void k_conv1(const float* __restrict__ yin,
                                               const float2* __restrict__ bnin,
                                               const float* __restrict__ w,
                                               const float* __restrict__ bb,
                                               float* __restrict__ yout,
                                               float2* __restrict__ part) {
    __shared__ __align__(16) float fAT[64 * 132];
    __shared__ __align__(16) float wT[64 * 68];
    __shared__ float bl[64], al[64], sl[64];
    int tid = threadIdx.x;
    int blk = blockIdx.x;
    int b = blk >> 8;
    int s0 = (blk & 255) << 2;
    size_t posbase = ((size_t)b * cS + s0) * cK;

    if (tid < 64) {
        bl[tid] = bb[tid];
        float2 t = bnin[tid];
        al[tid] = t.x; sl[tid] = t.y;
    }
    __syncthreads();
    for (int l = tid; l < 64 * 64; l += 256) {
        int o = l >> 6, c = l & 63;
        wT[c * 68 + o] = w[l];
    }
    {
        int r = tid >> 1, half = tid & 1;
        const float* yr = yin + (posbase + r) * 64 + half * 32;
#pragma unroll
        for (int q = 0; q < 8; q++) {
            float4 v = *(const float4*)(yr + q * 4);
            int c = half * 32 + q * 4;
            v.x = fmaxf(fmaf(v.x, al[c + 0], sl[c + 0]), 0.0f);
            v.y = fmaxf(fmaf(v.y, al[c + 1], sl[c + 1]), 0.0f);
            v.z = fmaxf(fmaf(v.z, al[c + 2], sl[c + 2]), 0.0f);
            v.w = fmaxf(fmaf(v.w, al[c + 3], sl[c + 3]), 0.0f);
            fAT[(c + 0) * 132 + r] = v.x;
            fAT[(c + 1) * 132 + r] = v.y;
            fAT[(c + 2) * 132 + r] = v.z;
            fAT[(c + 3) * 132 + r] = v.w;
        }
    }
    __syncthreads();

    int ry = tid >> 4, tx = tid & 15;
    float acc[8][4];
#pragma unroll
    for (int i = 0; i < 8; i++)
#pragma unroll
        for (int j = 0; j < 4; j++) acc[i][j] = bl[tx * 4 + j];

    for (int c = 0; c < 64; ++c) {
        const float* fb = fAT + c * 132;
        float4 a0 = *(const float4*)(fb + ry * 8);
        float4 a1 = *(const float4*)(fb + ry * 8 + 4);
        float4 wv = *(const float4*)&wT[c * 68 + tx * 4];
        float av[8] = {a0.x, a0.y, a0.z, a0.w, a1.x, a1.y, a1.z, a1.w};
#pragma unroll
        for (int i = 0; i < 8; i++) {
            acc[i][0] = fmaf(av[i], wv.x, acc[i][0]);
            acc[i][1] = fmaf(av[i], wv.y, acc[i][1]);
            acc[i][2] = fmaf(av[i], wv.z, acc[i][2]);
            acc[i][3] = fmaf(av[i], wv.w, acc[i][3]);
        }
    }
#pragma unroll
    for (int i = 0; i < 8; i++) {
        float4 o4 = make_float4(acc[i][0], acc[i][1], acc[i][2], acc[i][3]);
        *(float4*)(yout + (posbase + ry * 8 + i) * 64 + tx * 4) = o4;
    }
    __syncthreads();

    float* ps = wT;
    float* pq = wT + 16 * 64;
#pragma unroll
    for (int j = 0; j < 4; j++) {
        float s = 0.f, q = 0.f;
#pragma unroll
        for (int i = 0; i < 8; i++) { float v = acc[i][j]; s += v; q += v * v; }
        ps[ry * 64 + tx * 4 + j] = s;
        pq[ry * 64 + tx * 4 + j] = q;
    }
    __syncthreads();
    if (tid < 64) {
        float s = 0.f, q = 0.f;
        for (int t = 0; t < 16; t++) { s += ps[t * 64 + tid]; q += pq[t * 64 + tid]; }
        part[(size_t)blk * 64 + tid] = make_float2(s, q);
    }
}

// ---------------- conv2: 128 pos/block, 8x8 tile, both operands c-major ----------------
__global__ __launch_bounds__(256) void k_conv2(const float* __restrict__ y1,
                                               const float2* __restrict__ bn1,
                                               const float* __restrict__ w2,
                                               const float* __restrict__ b2,
                                               float* __restrict__ mx,
                                               float* __restrict__ mn,
                                               float2* __restrict__ part2) {
    __shared__ __align__(16) float fAT[64 * 132];
    __shared__ __align__(16) float wT[64 * 132];
    __shared__ float al[64], sl[64], bl[128];
    int tid = threadIdx.x;
    int blk = blockIdx.x;
    int b = blk >> 8;
    int s0 = (blk & 255) << 2;
    size_t posbase = ((size_t)b * cS + s0) * cK;

    if (tid < 64) { float2 t = bn1[tid]; al[tid] = t.x; sl[tid] = t.y; }
    if (tid < 128) bl[tid] = b2[tid];
    __syncthreads();

    {
        int r = tid >> 1, half = tid & 1;
        const float* yr = y1 + (posbase + r) * 64 + half * 32;
#pragma unroll
        for (int q = 0; q < 8; q++) {
            float4 v = *(const float4*)(yr + q * 4);
            int c = half * 32 + q * 4;
            v.x = fmaxf(fmaf(v.x, al[c + 0], sl[c + 0]), 0.0f);
            v.y = fmaxf(fmaf(v.y, al[c + 1], sl[c + 1]), 0.0f);
            v.z = fmaxf(fmaf(v.z, al[c + 2], sl[c + 2]), 0.0f);
            v.w = fmaxf(fmaf(v.w, al[c + 3], sl[c + 3]), 0.0f);
            fAT[(c + 0) * 132 + r] = v.x;
            fAT[(c + 1) * 132 + r] = v.y;
            fAT[(c + 2) * 132 + r] = v.z;
            fAT[(c + 3) * 132 + r] = v.w;
        }
    }
    for (int l = tid; l < 128 * 64; l += 256) {
        int o = l >> 6, c = l & 63;
        wT[c * 132 + o] = w2[l];
    }
    __syncthreads();

    int ry = tid >> 4, tx = tid & 15;
    float acc[8][8];
#pragma unroll
    for (int i = 0; i < 8; i++) {
#pragma unroll
        for (int j = 0; j < 4; j++) acc[i][j] = bl[tx * 4 + j];
#pragma unroll
        for (int j = 4; j < 8; j++) acc[i][j] = bl[64 + tx * 4 + (j - 4)];
    }

    for (int c = 0; c < 64; ++c) {
        const float* fb = fAT + c * 132;
        const float* wb = wT + c * 132;
        float4 a0 = *(const float4*)(fb + ry * 8);
        float4 a1 = *(const float4*)(fb + ry * 8 + 4);
        float4 w0v = *(const float4*)(wb + tx * 4);
        float4 w1v = *(const float4*)(wb + 64 + tx * 4);
        float av[8] = {a0.x, a0.y, a0.z, a0.w, a1.x, a1.y, a1.z, a1.w};
        float wv[8] = {w0v.x, w0v.y, w0v.z, w0v.w, w1v.x, w1v.y, w1v.z, w1v.w};
#pragma unroll
        for (int i = 0; i < 8; i++)
#pragma unroll
            for (int j = 0; j < 8; j++)
                acc[i][j] = fmaf(av[i], wv[j], acc[i][j]);
    }
    __syncthreads();

    float* ps  = wT;
    float* pq  = wT + 16 * 128;
    float* pmx = wT + 32 * 128;
    float* pmn = wT + 48 * 128;
#pragma unroll
    for (int j = 0; j < 8; j++) {
        int o = (j < 4) ? (tx * 4 + j) : (64 + tx * 4 + (j - 4));
        float s = 0.f, q = 0.f;
        float mv = -3.402823466e+38f, nv = 3.402823466e+38f;
#pragma unroll
        for (int i = 0; i < 8; i++) {
            float v = acc[i][j];
            s += v; q += v * v;
            mv = fmaxf(mv, v); nv = fminf(nv, v);
        }
        ps[ry * 128 + o] = s;
        pq[ry * 128 + o] = q;
        pmx[ry * 128 + o] = mv;
        pmn[ry * 128 + o] = nv;
    }
    __syncthreads();
    if (tid < 128) {
        float s = 0.f, q = 0.f;
        for (int t = 0; t < 16; t++) { s += ps[t * 128 + tid]; q += pq[t * 128 + tid]; }
        part2[(size_t)blk * 128 + tid] = make_float2(s, q);
    }
    for (int e = tid; e < 512; e += 256) {
        int sg = e >> 7, o = e & 127;
        float mv = -3.402823466e+38f, nv = 3.402823466e+38f;
        for (int t = sg * 4; t < sg * 4 + 4; ++t) {
            mv = fmaxf(mv, pmx[t * 128 + o]);
            nv = fminf(nv, pmn[t * 128 + o]);
        }
        int s = s0 + sg;
        mx[((size_t)b * cS + s) * 128 + o] = mv;
        mn[((size_t)b * cS + s) * 128 + o] = nv;
    }
}

// ---------------- BN finalize (float2 partials, f64 accumulate) ----------------
__global__ __launch_bounds__(256) void k_fin(const float2* __restrict__ part, int nblk,
                                             int oc,
                                             const float* __restrict__ g,
                                             const float* __restrict__ be,
                                             float2* __restrict__ bnout) {
    __shared__ double rs[256], rq[256];
    int o = blockIdx.x;
    int tid = threadIdx.x;
    double s = 0.0, q = 0.0;
    for (int i = tid; i < nblk; i += 256) {
        float2 p = part[(size_t)i * oc + o];
        s += (double)p.x;
        q += (double)p.y;
    }
    rs[tid] = s; rq[tid] = q;
    __syncthreads();
    for (int off = 128; off; off >>= 1) {
        if (tid < off) { rs[tid] += rs[tid + off]; rq[tid] += rq[tid + off]; }
        __syncthreads();
    }
    if (tid == 0) {
        double cntv = (double)PTOT;
        double mu = rs[0] / cntv;
        double var = rq[0] / cntv - mu * mu;
        if (var < 0.0) var = 0.0;
        float a = (float)((double)g[o] / sqrt(var + 1e-5));
        float sh = (float)((double)be[o] - mu * (double)a);
        bnout[o] = make_float2(a, sh);
    }
}

// ---------------- final: BN2(max_k y2)+ReLU -> new_points [B,128,S] ----------------
__global__ __launch_bounds__(256) void k_final(const float* __restrict__ mx,
                                               const float* __restrict__ mn,
                                               const float2* __restrict__ bn2,
                                               float* __restrict__ out1) {
    int i = blockIdx.x * 256 + threadIdx.x;
    int b = i >> 17;
    int r = i & ((1 << 17) - 1);
    int o = r >> 10;
    int s = r & 1023;
    float2 t = bn2[o];
    size_t idx = ((size_t)b * cS + s) * 128 + o;
    float M = (t.x >= 0.0f) ? mx[idx] : mn[idx];
    out1[i] = fmaxf(t.x * M + t.y, 0.0f);
}

// ---------------- launcher ----------------
extern "C" void kernel_launch(void* const* d_in, const int* in_sizes, int n_in,
                              void* d_out, int out_size, void* d_ws, size_t ws_size,
                              hipStream_t stream) {
    (void)in_sizes; (void)n_in; (void)out_size;
    const float* xyz = (const float*)d_in[0];
    const float* pts = (const float*)d_in[1];
    const int* sidx  = (const int*)d_in[2];
    const float* w0  = (const float*)d_in[3];
    const float* b0  = (const float*)d_in[4];
    const float* g0  = (const float*)d_in[5];
    const float* be0 = (const float*)d_in[6];
    const float* w1  = (const float*)d_in[7];
    const float* b1  = (const float*)d_in[8];
    const float* g1  = (const float*)d_in[9];
    const float* be1 = (const float*)d_in[10];
    const float* w2  = (const float*)d_in[11];
    const float* b2  = (const float*)d_in[12];
    const float* g2  = (const float*)d_in[13];
    const float* be2 = (const float*)d_in[14];
    float* out = (float*)d_out;
    char* ws = (char*)d_ws;
    if (ws_size < WS_END) return;

    float* ptsT  = (float*)(ws + WS_PTS);
    float4* xyzp = (float4*)(ws + WS_XYZP);
    int* idxw    = (int*)(ws + WS_IDX);
    float* normw = (float*)(ws + WS_NORM);
    float* y0    = (float*)(ws + WS_Y0);
    float* y1    = (float*)(ws + WS_Y1);
    float* mx    = (float*)(ws + WS_MX);
    float* mn    = (float*)(ws + WS_MN);
    float2* p0   = (float2*)(ws + WS_P0);
    float2* p1   = (float2*)(ws + WS_P1);
    float2* p2   = (float2*)(ws + WS_P2);
    float2* bnb  = (float2*)(ws + WS_BN);

    hipLaunchKernelGGL(k_prep, dim3(2048 + cB * cN / 256), dim3(256), 0, stream,
                       pts, xyz, ptsT, xyzp);
    hipLaunchKernelGGL(k_knn, dim3(cB * cS / QB), dim3(256), 0, stream,
                       xyz, sidx, xyzp, idxw, normw, out);
    hipLaunchKernelGGL(k_conv0, dim3(NBLK2), dim3(256), 0, stream,
                       idxw, normw, ptsT, w0, b0, y0, p0);
    hipLaunchKernelGGL(k_fin, dim3(64), dim3(256), 0, stream, p0, NBLK2, 64, g0, be0, bnb);
    hipLaunchKernelGGL(k_conv1, dim3(NBLK2), dim3(256), 0, stream, y0, bnb, w1, b1, y1, p1);
    hipLaunchKernelGGL(k_fin, dim3(64), dim3(256), 0, stream, p1, NBLK2, 64, g1, be1, bnb + 128);
    hipLaunchKernelGGL(k_conv2, dim3(NBLK2), dim3(256), 0, stream,
                       y1, bnb + 128, w2, b2, mx, mn, p2);
    hipLaunchKernelGGL(k_fin, dim3(128), dim3(256), 0, stream, p2, NBLK2, 128, g2, be2, bnb + 256);
    hipLaunchKernelGGL(k_final, dim3(cB * cO2 * cS / 256), dim3(256), 0, stream,
                       mx, mn, bnb + 256, out + OUT1_OFF);
}